// Round 3
// baseline (2676.038 us; speedup 1.0000x reference)
//
#include <hip/hip_runtime.h>
#include <math.h>

typedef __attribute__((ext_vector_type(8))) short  short8;
typedef __attribute__((ext_vector_type(4))) float  f32x4;
typedef unsigned short ushort;

#define S_DIM 256
#define L_DIM 512
#define E_DIM 512
#define H_DIM 4
#define HD    128
#define M_DIM (S_DIM * L_DIM)   // 131072

// ---------------- numeric helpers ----------------
__device__ inline ushort f2bf_rne(float f) {
    unsigned u = __float_as_uint(f);
    unsigned r = (u + 0x7FFFu + ((u >> 16) & 1u)) >> 16;
    return (ushort)r;
}
// split f into hi (truncated bf16) + lo (bf16 of remainder); hi+lo ~ f to ~2^-16 rel
__device__ inline void split2(float f, ushort& hi, ushort& lo) {
    unsigned u = __float_as_uint(f);
    hi = (ushort)(u >> 16);
    float fhi = __uint_as_float(u & 0xFFFF0000u);
    float fl = f - fhi;
    lo = (ushort)(__float_as_uint(fl) >> 16);
}

// ---------------------------------------------------------------------------
// Kernel 1: banded Q/K generation + split to bf16 hi/lo; also emits x as bf16.
// out[s,t,e] = x[s,t,e] + sum_{u=t-n1+1..t-1} x[s,u,e]*coef1[u,e]
//                       + sum_{u=t+1..t+n2-1} x[s,u,e]*coef2[u,e]
// Streaming sliding-window per (s,e) thread (prefix-difference recurrence).
// ---------------------------------------------------------------------------
__global__ __launch_bounds__(256) void banded_split_kernel(
    const float* __restrict__ x, const float* __restrict__ a,
    const float* __restrict__ b, const float* __restrict__ c,
    const float* __restrict__ d, const int* __restrict__ n1p,
    const int* __restrict__ n2p,
    ushort* __restrict__ Qhi, ushort* __restrict__ Qlo,
    ushort* __restrict__ Khi, ushort* __restrict__ Klo,
    ushort* __restrict__ xhi)
{
    const int e = blockIdx.x * 256 + threadIdx.x;
    const int s = blockIdx.y;
    const int n1 = *n1p, n2 = *n2p;
    const float* xs = x + (size_t)s * L_DIM * E_DIM + e;
    const size_t ob = (size_t)s * L_DIM * E_DIM + e;

    float bq = 0.f, bk = 0.f;
    const int jmax = min(n2 - 1, L_DIM - 1);
    for (int j = 1; j <= jmax; ++j) {
        float xv = xs[(size_t)j * E_DIM];
        bq += xv * c[j * E_DIM + e];
        bk += xv * d[j * E_DIM + e];
    }
    float fq = 0.f, fk = 0.f;
    float xprev = 0.f;
    for (int t = 0; t < L_DIM; ++t) {
        float xc = xs[(size_t)t * E_DIM];
        if (t > 0) {
            fq += xprev * a[(t - 1) * E_DIM + e];
            fk += xprev * b[(t - 1) * E_DIM + e];
            int tr = t - n1;
            if (tr >= 0) {
                float xt = xs[(size_t)tr * E_DIM];
                fq -= xt * a[tr * E_DIM + e];
                fk -= xt * b[tr * E_DIM + e];
            }
            bq -= xc * c[t * E_DIM + e];
            bk -= xc * d[t * E_DIM + e];
            int th = t + n2 - 1;
            if (th <= L_DIM - 1) {
                float xh = xs[(size_t)th * E_DIM];
                bq += xh * c[th * E_DIM + e];
                bk += xh * d[th * E_DIM + e];
            }
        }
        float qv = xc + fq + bq;
        float kv = xc + fk + bk;
        size_t o = ob + (size_t)t * E_DIM;
        ushort h_, l_;
        split2(qv, h_, l_); Qhi[o] = h_; Qlo[o] = l_;
        split2(kv, h_, l_); Khi[o] = h_; Klo[o] = l_;
        xhi[o] = f2bf_rne(xc);
        xprev = xc;
    }
}

// ---------------------------------------------------------------------------
// Kernel 2: split weights (in_proj_w 786432 + out_w 262144 floats) to bf16 hi/lo
// ---------------------------------------------------------------------------
__global__ __launch_bounds__(256) void split_weights(
    const float* __restrict__ ipw, const float* __restrict__ ow,
    ushort* __restrict__ whi, ushort* __restrict__ wlo)
{
    const int NIP = 3 * E_DIM * E_DIM;
    const int TOT = NIP + E_DIM * E_DIM;
    int idx = blockIdx.x * 256 + threadIdx.x;
    if (idx >= TOT) return;
    float v = (idx < NIP) ? ipw[idx] : ow[idx - NIP];
    ushort h_, l_;
    split2(v, h_, l_);
    whi[idx] = h_; wlo[idx] = l_;
}

// ---------------------------------------------------------------------------
// Kernel 3: MFMA GEMM  C = A (Mx512) * W^T (512x512) + bias, A/W in split bf16.
// Tile 128x128, BK=32, 4 waves, each wave 64x64 (4x4 frags of 16x16x32).
// SPLIT: acc += Ahi*Whi + Alo*Whi + Ahi*Wlo  (3 mfma per frag pair)
// MODE 0: fp32 row-major out.  MODE 1: split bf16 -> [L][H][S][HD] hi/lo.
// MODE 2: plain bf16 -> [L][H][S][HD].
// LDS row stride 40 elems (80B): 16B-aligned, <=2-way banks (free per m136).
// XCD-aware swizzle: the 4 n-blocks sharing an A-panel land on one XCD's L2.
// ---------------------------------------------------------------------------
template <int MODE, int SPLIT>
__global__ __launch_bounds__(256) void gemm_mfma(
    const ushort* __restrict__ Ahi, const ushort* __restrict__ Alo,
    const ushort* __restrict__ Whi, const ushort* __restrict__ Wlo,
    const float* __restrict__ bias,
    ushort* __restrict__ out_hi, ushort* __restrict__ out_lo,
    float* __restrict__ out_f)
{
    __shared__ ushort lds[SPLIT ? 20480 : 10240];
    ushort* Ah = lds;               // 128*40
    ushort* Wh = lds + 5120;
    ushort* Al = lds + (SPLIT ? 10240 : 0);
    ushort* Wl = lds + (SPLIT ? 15360 : 0);

    const int tid = threadIdx.x;
    // bijective XCD swizzle (nwg=4096, %8==0): hw-linear id -> chunked work id
    const int wid = blockIdx.y * 4 + blockIdx.x;
    const int work = (wid & 7) * 512 + (wid >> 3);
    const int m0 = (work >> 2) * 128;
    const int n0 = (work & 3) * 128;
    const int l = tid & 63, w = tid >> 6;
    const int wm = w >> 1, wn = w & 1;
    const int lane16 = l & 15, hi4 = l >> 4;

    f32x4 zz = {0.f, 0.f, 0.f, 0.f};
    f32x4 acc[4][4];
#pragma unroll
    for (int i = 0; i < 4; ++i)
#pragma unroll
        for (int j = 0; j < 4; ++j) acc[i][j] = zz;

    const int row0 = tid >> 2, row1 = row0 + 64;
    const int ck = (tid & 3) * 8;

    for (int k0 = 0; k0 < 512; k0 += 32) {
        short8 ra0 = *(const short8*)&Ahi[(size_t)(m0 + row0) * 512 + k0 + ck];
        short8 ra1 = *(const short8*)&Ahi[(size_t)(m0 + row1) * 512 + k0 + ck];
        short8 rw0 = *(const short8*)&Whi[(size_t)(n0 + row0) * 512 + k0 + ck];
        short8 rw1 = *(const short8*)&Whi[(size_t)(n0 + row1) * 512 + k0 + ck];
        short8 sa0, sa1, sw0, sw1;
        if constexpr (SPLIT) {
            sa0 = *(const short8*)&Alo[(size_t)(m0 + row0) * 512 + k0 + ck];
            sa1 = *(const short8*)&Alo[(size_t)(m0 + row1) * 512 + k0 + ck];
            sw0 = *(const short8*)&Wlo[(size_t)(n0 + row0) * 512 + k0 + ck];
            sw1 = *(const short8*)&Wlo[(size_t)(n0 + row1) * 512 + k0 + ck];
        }
        __syncthreads();
        *(short8*)&Ah[row0 * 40 + ck] = ra0;
        *(short8*)&Ah[row1 * 40 + ck] = ra1;
        *(short8*)&Wh[row0 * 40 + ck] = rw0;
        *(short8*)&Wh[row1 * 40 + ck] = rw1;
        if constexpr (SPLIT) {
            *(short8*)&Al[row0 * 40 + ck] = sa0;
            *(short8*)&Al[row1 * 40 + ck] = sa1;
            *(short8*)&Wl[row0 * 40 + ck] = sw0;
            *(short8*)&Wl[row1 * 40 + ck] = sw1;
        }
        __syncthreads();

        short8 ah[4], bh[4], al_[4], bl_[4];
#pragma unroll
        for (int mi = 0; mi < 4; ++mi)
            ah[mi] = *(const short8*)&Ah[(wm * 64 + mi * 16 + lane16) * 40 + hi4 * 8];
#pragma unroll
        for (int ni = 0; ni < 4; ++ni)
            bh[ni] = *(const short8*)&Wh[(wn * 64 + ni * 16 + lane16) * 40 + hi4 * 8];
        if constexpr (SPLIT) {
#pragma unroll
            for (int mi = 0; mi < 4; ++mi)
                al_[mi] = *(const short8*)&Al[(wm * 64 + mi * 16 + lane16) * 40 + hi4 * 8];
#pragma unroll
            for (int ni = 0; ni < 4; ++ni)
                bl_[ni] = *(const short8*)&Wl[(wn * 64 + ni * 16 + lane16) * 40 + hi4 * 8];
        }
#pragma unroll
        for (int mi = 0; mi < 4; ++mi)
#pragma unroll
            for (int ni = 0; ni < 4; ++ni) {
                acc[mi][ni] = __builtin_amdgcn_mfma_f32_16x16x32_bf16(
                    ah[mi], bh[ni], acc[mi][ni], 0, 0, 0);
                if constexpr (SPLIT) {
                    acc[mi][ni] = __builtin_amdgcn_mfma_f32_16x16x32_bf16(
                        al_[mi], bh[ni], acc[mi][ni], 0, 0, 0);
                    acc[mi][ni] = __builtin_amdgcn_mfma_f32_16x16x32_bf16(
                        ah[mi], bl_[ni], acc[mi][ni], 0, 0, 0);
                }
            }
    }

    // epilogue: C/D frag mapping col=lane&15, row=(lane>>4)*4+reg (m89-verified)
#pragma unroll
    for (int mi = 0; mi < 4; ++mi) {
#pragma unroll
        for (int ni = 0; ni < 4; ++ni) {
            const int col = n0 + wn * 64 + ni * 16 + lane16;
            const float bs = bias[col];
#pragma unroll
            for (int r = 0; r < 4; ++r) {
                const int row = m0 + wm * 64 + mi * 16 + hi4 * 4 + r;
                float v = acc[mi][ni][r] + bs;
                if (MODE == 0) {
                    out_f[(size_t)row * 512 + col] = v;
                } else {
                    const int s = row >> 9, nb = row & 511;
                    const int h = col >> 7, dd = col & 127;
                    const size_t o =
                        (((size_t)nb * H_DIM + h) * S_DIM + s) * HD + dd;
                    if (MODE == 1) {
                        ushort h_, l_;
                        split2(v, h_, l_);
                        out_hi[o] = h_; out_lo[o] = l_;
                    } else {
                        out_hi[o] = f2bf_rne(v);
                    }
                }
            }
        }
    }
}

// ---------------------------------------------------------------------------
// Kernel 4: per-(n,h) transpose vp [s][d] -> vpT [d][s]  (bf16)
// ---------------------------------------------------------------------------
__global__ __launch_bounds__(256) void transpose_v(
    const ushort* __restrict__ vin, ushort* __restrict__ vout)
{
    __shared__ ushort T[128 * 136];
    const int tid = threadIdx.x;
    const int s0 = blockIdx.x * 128;
    const int nh = blockIdx.y;
    const size_t ib = (size_t)nh * S_DIM * HD;

#pragma unroll
    for (int p = 0; p < 8; ++p) {
        int row = (tid >> 4) + p * 16;
        int cc = (tid & 15) * 8;
        *(short8*)&T[row * 136 + cc] =
            *(const short8*)&vin[ib + (size_t)(s0 + row) * HD + cc];
    }
    __syncthreads();
    const int dr = tid >> 1;
    const int sh = (tid & 1) * 64;
#pragma unroll
    for (int j = 0; j < 8; ++j) {
        short8 v;
#pragma unroll
        for (int e = 0; e < 8; ++e)
            ((ushort*)&v)[e] = T[(sh + j * 8 + e) * 136 + dr];
        *(short8*)&vout[ib + (size_t)dr * S_DIM + s0 + sh + j * 8] = v;
    }
}

// ---------------------------------------------------------------------------
// Kernel 5: MFMA flash attention per (s-tile 64, h, n).
// qp/kp: [n][h][s][d] split bf16; vpT: [n][h][d][s] bf16.
// 4 waves; wave w owns 16 s-rows. Q in registers; K hi/lo + V^T in LDS.
// Split QK^T (3 mfma), in-register online softmax (score rows align with
// lane groups for both QK^T-D and PV-D, so m/l/alpha stay in-lane), bf16 PV.
// Output o (S,L,E) as split bf16 hi/lo.
// XCD swizzle: 4 s-blocks sharing a (h,n) head land on one XCD's L2.
// ---------------------------------------------------------------------------
__global__ __launch_bounds__(256) void attn_mfma(
    const ushort* __restrict__ qphi, const ushort* __restrict__ qplo,
    const ushort* __restrict__ kphi, const ushort* __restrict__ kplo,
    const ushort* __restrict__ vpT,
    ushort* __restrict__ ohi, ushort* __restrict__ olo)
{
    __shared__ ushort Kh[64 * 136];
    __shared__ ushort Kl[64 * 136];
    __shared__ ushort VT[128 * 72];
    __shared__ ushort Pl[4 * 16 * 72];

    const int tid = threadIdx.x;
    const int l = tid & 63, w = tid >> 6;
    const int lane16 = l & 15, hi4 = l >> 4;
    // bijective XCD swizzle (nwg=8192, %8==0)
    const int wid = (blockIdx.z * 4 + blockIdx.y) * 4 + blockIdx.x;
    const int work = (wid & 7) * 1024 + (wid >> 3);
    const int s0 = (work & 3) * 64;
    const int h = (work >> 2) & 3;
    const int n = work >> 4;
    const int nh = n * H_DIM + h;
    const size_t qb = (size_t)nh * S_DIM * HD;
    const size_t vb = (size_t)nh * HD * S_DIM;
    const float scale = 0.08838834764831845f;  // 1/sqrt(128)

    // Q fragments in registers (wave's 16 s-rows)
    short8 qh[4], ql[4];
    {
        const size_t rb = qb + (size_t)(s0 + w * 16 + lane16) * HD + hi4 * 8;
#pragma unroll
        for (int ks = 0; ks < 4; ++ks) {
            qh[ks] = *(const short8*)&qphi[rb + ks * 32];
            ql[ks] = *(const short8*)&qplo[rb + ks * 32];
        }
    }

    float mreg[4] = {-1e30f, -1e30f, -1e30f, -1e30f};
    float lreg[4] = {0.f, 0.f, 0.f, 0.f};
    f32x4 zz = {0.f, 0.f, 0.f, 0.f};
    f32x4 Ob[8];
#pragma unroll
    for (int di = 0; di < 8; ++di) Ob[di] = zz;

    ushort* Pw = Pl + w * 1152;  // 16*72

    for (int t0 = 0; t0 < S_DIM; t0 += 64) {
        __syncthreads();
        {   // stage K hi/lo tile [64][136]
            const int row = tid >> 2;
            const int cb = tid & 3;
#pragma unroll
            for (int p = 0; p < 4; ++p) {
                const int chunk = p * 4 + cb;
                const size_t g = qb + (size_t)(t0 + row) * HD + chunk * 8;
                *(short8*)&Kh[row * 136 + chunk * 8] = *(const short8*)&kphi[g];
                *(short8*)&Kl[row * 136 + chunk * 8] = *(const short8*)&kplo[g];
            }
            // stage V^T tile [128][72] (cols t0..t0+63)
            const int dr = tid >> 1;
            const int cb2 = (tid & 1) * 4;
#pragma unroll
            for (int p = 0; p < 4; ++p) {
                const int chunk = cb2 + p;
                const size_t g = vb + (size_t)dr * S_DIM + t0 + chunk * 8;
                *(short8*)&VT[dr * 72 + chunk * 8] = *(const short8*)&vpT[g];
            }
        }
        __syncthreads();

        // QK^T: D[s(16) x t(64)] per wave, split precision
        f32x4 sc[4];
#pragma unroll
        for (int ni = 0; ni < 4; ++ni) sc[ni] = zz;
#pragma unroll
        for (int ks = 0; ks < 4; ++ks) {
#pragma unroll
            for (int ni = 0; ni < 4; ++ni) {
                const int ko = (ni * 16 + lane16) * 136 + ks * 32 + hi4 * 8;
                short8 bh = *(const short8*)&Kh[ko];
                short8 bl = *(const short8*)&Kl[ko];
                sc[ni] = __builtin_amdgcn_mfma_f32_16x16x32_bf16(qh[ks], bh, sc[ni], 0, 0, 0);
                sc[ni] = __builtin_amdgcn_mfma_f32_16x16x32_bf16(ql[ks], bh, sc[ni], 0, 0, 0);
                sc[ni] = __builtin_amdgcn_mfma_f32_16x16x32_bf16(qh[ks], bl, sc[ni], 0, 0, 0);
            }
        }

        // online softmax; lane holds rows hi4*4+r, cols ni*16+lane16
        float pm[4];
#pragma unroll
        for (int r = 0; r < 4; ++r) {
            pm[r] = fmaxf(fmaxf(sc[0][r], sc[1][r]), fmaxf(sc[2][r], sc[3][r])) * scale;
            pm[r] = fmaxf(pm[r], __shfl_xor(pm[r], 1));
            pm[r] = fmaxf(pm[r], __shfl_xor(pm[r], 2));
            pm[r] = fmaxf(pm[r], __shfl_xor(pm[r], 4));
            pm[r] = fmaxf(pm[r], __shfl_xor(pm[r], 8));
        }
#pragma unroll
        for (int r = 0; r < 4; ++r) {
            const float mn = fmaxf(mreg[r], pm[r]);
            const float alpha = __expf(mreg[r] - mn);
            mreg[r] = mn;
            float ps = 0.f;
#pragma unroll
            for (int ni = 0; ni < 4; ++ni) {
                float p = __expf(sc[ni][r] * scale - mn);
                ps += p;
                Pw[(hi4 * 4 + r) * 72 + ni * 16 + lane16] = f2bf_rne(p);
            }
            ps += __shfl_xor(ps, 1);
            ps += __shfl_xor(ps, 2);
            ps += __shfl_xor(ps, 4);
            ps += __shfl_xor(ps, 8);
            lreg[r] = lreg[r] * alpha + ps;
#pragma unroll
            for (int di = 0; di < 8; ++di) Ob[di][r] *= alpha;
        }

        // PV: O[s(16) x d(128)] += P[s x 64] * V[64 x d]
#pragma unroll
        for (int ks = 0; ks < 2; ++ks) {
            short8 pa = *(const short8*)&Pw[lane16 * 72 + ks * 32 + hi4 * 8];
#pragma unroll
            for (int di = 0; di < 8; ++di) {
                short8 bv = *(const short8*)&VT[(di * 16 + lane16) * 72 + ks * 32 + hi4 * 8];
                Ob[di] = __builtin_amdgcn_mfma_f32_16x16x32_bf16(pa, bv, Ob[di], 0, 0, 0);
            }
        }
    }

    // epilogue: o (S,L,E) split bf16
#pragma unroll
    for (int r = 0; r < 4; ++r) {
        const float inv = 1.0f / lreg[r];
        const int so = s0 + w * 16 + hi4 * 4 + r;
#pragma unroll
        for (int di = 0; di < 8; ++di) {
            float v = Ob[di][r] * inv;
            ushort h_, l_;
            split2(v, h_, l_);
            const size_t o = ((size_t)so * L_DIM + n) * E_DIM + h * HD + di * 16 + lane16;
            ohi[o] = h_; olo[o] = l_;
        }
    }
}

// ---------------------------------------------------------------------------
// Buffer lifetime plan (7 x 128MiB bf16 buffers + 4MiB weights = 900MiB):
//   B0 xhi      -> (after vp GEMM consumes it) ohi
//   B1 Qhi      -> (after qp GEMM)             kphi
//   B2 Qlo      -> (after qp GEMM)             kplo
//   B3 Khi      -> (after kp GEMM)             vpn  -> (after transpose) olo
//   B4 Klo      -> (after kp GEMM)             vpT
//   B5 qphi, B6 qplo
// ---------------------------------------------------------------------------
extern "C" void kernel_launch(void* const* d_in, const int* in_sizes, int n_in,
                              void* d_out, int out_size, void* d_ws, size_t ws_size,
                              hipStream_t stream) {
    (void)in_sizes; (void)n_in; (void)out_size; (void)ws_size;
    const float* x   = (const float*)d_in[0];
    const float* a   = (const float*)d_in[1];
    const float* b   = (const float*)d_in[2];
    const float* c   = (const float*)d_in[3];
    const float* d   = (const float*)d_in[4];
    const float* ipw = (const float*)d_in[5];
    const float* ipb = (const float*)d_in[6];
    const float* ow  = (const float*)d_in[7];
    const float* ob  = (const float*)d_in[8];
    const int* n1    = (const int*)d_in[9];
    const int* n2    = (const int*)d_in[10];

    ushort* W0 = (ushort*)d_ws;
    const size_t BUF = (size_t)M_DIM * E_DIM;  // 67108864 elems (128MiB bf16)
    ushort* B0 = W0;
    ushort* B1 = W0 + 1 * BUF;
    ushort* B2 = W0 + 2 * BUF;
    ushort* B3 = W0 + 3 * BUF;
    ushort* B4 = W0 + 4 * BUF;
    ushort* B5 = W0 + 5 * BUF;
    ushort* B6 = W0 + 6 * BUF;
    ushort* WH = W0 + 7 * BUF;          // 1048576 elems
    ushort* WL = WH + 1048576;

    ushort *xhi = B0, *Qhi = B1, *Qlo = B2, *Khi = B3, *Klo = B4;
    ushort *qphi = B5, *qplo = B6;
    ushort *kphi = B1, *kplo = B2;      // reuse Q after qp GEMM
    ushort *vpn = B3, *vpT = B4;        // reuse K after kp GEMM
    ushort *ohi = B0, *olo = B3;        // reuse xhi/vpn after attention inputs done

    // 1) banded Q/K + splits (+ x -> bf16)
    banded_split_kernel<<<dim3(2, 256), 256, 0, stream>>>(
        x, a, b, c, d, n1, n2, Qhi, Qlo, Khi, Klo, xhi);

    // 2) weight splits
    split_weights<<<dim3(4096), 256, 0, stream>>>(ipw, ow, WH, WL);

    // 3) projections into per-head layout [L][H][S][HD]
    gemm_mfma<1, 1><<<dim3(4, 1024), 256, 0, stream>>>(
        Qhi, Qlo, WH, WL, ipb, qphi, qplo, nullptr);
    gemm_mfma<1, 1><<<dim3(4, 1024), 256, 0, stream>>>(
        Khi, Klo, WH + 262144, WL + 262144, ipb + 512, kphi, kplo, nullptr);
    gemm_mfma<2, 0><<<dim3(4, 1024), 256, 0, stream>>>(
        xhi, nullptr, WH + 524288, nullptr, ipb + 1024, vpn, nullptr, nullptr);

    // 4) V transpose per head: [n][h][s][d] -> [n][h][d][s]
    transpose_v<<<dim3(2, 2048), 256, 0, stream>>>(vpn, vpT);

    // 5) attention -> o (S,L,E) split bf16
    attn_mfma<<<dim3(4, 4, 512), 256, 0, stream>>>(
        qphi, qplo, kphi, kplo, vpT, ohi, olo);

    // 6) out projection -> fp32 d_out
    gemm_mfma<0, 1><<<dim3(4, 1024), 256, 0, stream>>>(
        ohi, olo, WH + 786432, WL + 786432, ob, nullptr, nullptr, (float*)d_out);
}

// Round 4
// 2275.850 us; speedup vs baseline: 1.1758x; 1.1758x over previous
//
#include <hip/hip_runtime.h>
#include <math.h>

typedef __attribute__((ext_vector_type(8))) short  short8;
typedef __attribute__((ext_vector_type(4))) float  f32x4;
typedef unsigned short ushort;

#define S_DIM 256
#define L_DIM 512
#define E_DIM 512
#define H_DIM 4
#define HD    128
#define M_DIM (S_DIM * L_DIM)   // 131072

#define CH    32                 // banded t-chunk
#define NCH   (L_DIM / CH)       // 16
#define CSN   ((size_t)S_DIM * NCH * E_DIM)   // per-array chunk-sum count

// ---------------- numeric helpers ----------------
__device__ inline ushort f2bf_rne(float f) {
    unsigned u = __float_as_uint(f);
    unsigned r = (u + 0x7FFFu + ((u >> 16) & 1u)) >> 16;
    return (ushort)r;
}
// split f into hi (truncated bf16) + lo (bf16 of remainder); hi+lo ~ f to ~2^-16 rel
__device__ inline void split2(float f, ushort& hi, ushort& lo) {
    unsigned u = __float_as_uint(f);
    hi = (ushort)(u >> 16);
    float fhi = __uint_as_float(u & 0xFFFF0000u);
    float fl = f - fhi;
    lo = (ushort)(__float_as_uint(fl) >> 16);
}

// ---------------------------------------------------------------------------
// Kernel 1a: per-chunk partial sums of the 4 weighted streams + x -> bf16.
// CS layout: CS[arr][s][cz][e], arr: 0=x*a 1=x*b 2=x*c 3=x*d
// Grid (2, 256, 16), block 256. Thread = (e, s, chunk).
// ---------------------------------------------------------------------------
__global__ __launch_bounds__(256) void banded_chunksums(
    const float* __restrict__ x, const float* __restrict__ a,
    const float* __restrict__ b, const float* __restrict__ c,
    const float* __restrict__ d, float* __restrict__ CS,
    ushort* __restrict__ xhi)
{
    const int e = blockIdx.x * 256 + threadIdx.x;
    const int s = blockIdx.y;
    const int cz = blockIdx.z;
    const float* xs = x + (size_t)s * L_DIM * E_DIM + e;
    const int u0 = cz * CH;

    float s1q = 0.f, s1k = 0.f, s2q = 0.f, s2k = 0.f;
#pragma unroll 4
    for (int i = 0; i < CH; ++i) {
        const int u = u0 + i;
        const float xv = xs[(size_t)u * E_DIM];
        s1q += xv * a[u * E_DIM + e];
        s1k += xv * b[u * E_DIM + e];
        s2q += xv * c[u * E_DIM + e];
        s2k += xv * d[u * E_DIM + e];
        xhi[(size_t)s * L_DIM * E_DIM + (size_t)u * E_DIM + e] = f2bf_rne(xv);
    }
    const size_t base = ((size_t)s * NCH + cz) * E_DIM + e;
    CS[base]           = s1q;
    CS[CSN + base]     = s1k;
    CS[2 * CSN + base] = s2q;
    CS[3 * CSN + base] = s2k;
}

// ---------------------------------------------------------------------------
// Kernel 1b: banded outputs for one t-chunk, init via edge loops + chunk sums,
// then the 32-step sliding recurrence. Emits split-bf16 Q and K.
// out[s,t,e] = x[t] + sum_{u=max(t-n1+1,0)}^{t-1} x[u]*coef1[u]
//                   + sum_{u=t+1}^{min(t+n2-1,L-1)} x[u]*coef2[u]
// ---------------------------------------------------------------------------
__global__ __launch_bounds__(256) void banded_out(
    const float* __restrict__ x, const float* __restrict__ a,
    const float* __restrict__ b, const float* __restrict__ c,
    const float* __restrict__ d, const int* __restrict__ n1p,
    const int* __restrict__ n2p, const float* __restrict__ CS,
    ushort* __restrict__ Qhi, ushort* __restrict__ Qlo,
    ushort* __restrict__ Khi, ushort* __restrict__ Klo)
{
    const int e = blockIdx.x * 256 + threadIdx.x;
    const int s = blockIdx.y;
    const int cz = blockIdx.z;
    const int c0 = cz * CH;
    const int n1 = *n1p, n2 = *n2p;
    const float* xs = x + (size_t)s * L_DIM * E_DIM + e;
    const size_t csb = (size_t)s * NCH * E_DIM + e;

    float fq = 0.f, fk = 0.f, bq = 0.f, bk = 0.f;

    // ---- fwd init: window [max(0, c0-n1+1), c0-1] ----
    if (c0 > 0) {
        const int lo = max(0, c0 - n1 + 1);
        const int czA = (lo + CH - 1) >> 5;          // first full chunk
        const int eend = min(c0, czA * CH);
        for (int u = lo; u < eend; ++u) {
            const float xv = xs[(size_t)u * E_DIM];
            fq += xv * a[u * E_DIM + e];
            fk += xv * b[u * E_DIM + e];
        }
        for (int j = czA; j < cz; ++j) {
            const size_t cb = csb + (size_t)j * E_DIM;
            fq += CS[cb];
            fk += CS[CSN + cb];
        }
    }
    // ---- bwd init: window [c0+1, min(L-1, c0+n2-1)] ----
    {
        const int hi = min(L_DIM - 1, c0 + n2 - 1);
        const int bend = min(hi, c0 + CH - 1);       // bottom edge inside own chunk
        for (int u = c0 + 1; u <= bend; ++u) {
            const float xv = xs[(size_t)u * E_DIM];
            bq += xv * c[u * E_DIM + e];
            bk += xv * d[u * E_DIM + e];
        }
        const int czE = (hi + 1) >> 5;               // chunks cz+1..czE-1 are full
        for (int j = cz + 1; j < czE; ++j) {
            const size_t cb = csb + (size_t)j * E_DIM;
            bq += CS[2 * CSN + cb];
            bk += CS[3 * CSN + cb];
        }
        if (czE >= cz + 1) {                          // top partial edge
            for (int u = czE * CH; u <= hi; ++u) {
                const float xv = xs[(size_t)u * E_DIM];
                bq += xv * c[u * E_DIM + e];
                bk += xv * d[u * E_DIM + e];
            }
        }
    }

    // ---- slide over the chunk ----
    const size_t ob = (size_t)s * L_DIM * E_DIM + e;
    float xprev = 0.f;
    for (int tt = 0; tt < CH; ++tt) {
        const int t = c0 + tt;
        const float xc = xs[(size_t)t * E_DIM];
        if (tt > 0) {
            fq += xprev * a[(t - 1) * E_DIM + e];
            fk += xprev * b[(t - 1) * E_DIM + e];
            const int tr = t - n1;
            if (tr >= 0) {
                const float xt = xs[(size_t)tr * E_DIM];
                fq -= xt * a[tr * E_DIM + e];
                fk -= xt * b[tr * E_DIM + e];
            }
            bq -= xc * c[t * E_DIM + e];
            bk -= xc * d[t * E_DIM + e];
            const int th = t + n2 - 1;
            if (th <= L_DIM - 1) {
                const float xh = xs[(size_t)th * E_DIM];
                bq += xh * c[th * E_DIM + e];
                bk += xh * d[th * E_DIM + e];
            }
        }
        const float qv = xc + fq + bq;
        const float kv = xc + fk + bk;
        const size_t o = ob + (size_t)t * E_DIM;
        ushort h_, l_;
        split2(qv, h_, l_); Qhi[o] = h_; Qlo[o] = l_;
        split2(kv, h_, l_); Khi[o] = h_; Klo[o] = l_;
        xprev = xc;
    }
}

// ---------------------------------------------------------------------------
// Kernel 2: split weights (in_proj_w 786432 + out_w 262144 floats) to bf16 hi/lo
// ---------------------------------------------------------------------------
__global__ __launch_bounds__(256) void split_weights(
    const float* __restrict__ ipw, const float* __restrict__ ow,
    ushort* __restrict__ whi, ushort* __restrict__ wlo)
{
    const int NIP = 3 * E_DIM * E_DIM;
    const int TOT = NIP + E_DIM * E_DIM;
    int idx = blockIdx.x * 256 + threadIdx.x;
    if (idx >= TOT) return;
    float v = (idx < NIP) ? ipw[idx] : ow[idx - NIP];
    ushort h_, l_;
    split2(v, h_, l_);
    whi[idx] = h_; wlo[idx] = l_;
}

// ---------------------------------------------------------------------------
// Kernel 3: MFMA GEMM  C = A (Mx512) * W^T (512x512) + bias, A/W in split bf16.
// Tile 128x128, BK=32, 4 waves, each wave 64x64 (4x4 frags of 16x16x32).
// SPLIT: acc += Ahi*Whi + Alo*Whi + Ahi*Wlo  (3 mfma per frag pair)
// MODE 0: fp32 row-major out.  MODE 1: split bf16 -> [L][H][S][HD] hi/lo.
// MODE 2: plain bf16 -> [L][H][S][HD].
// LDS row stride 40 elems (80B): 16B-aligned, <=2-way banks (free per m136).
// XCD-aware swizzle: the 4 n-blocks sharing an A-panel land on one XCD's L2.
// ---------------------------------------------------------------------------
template <int MODE, int SPLIT>
__global__ __launch_bounds__(256) void gemm_mfma(
    const ushort* __restrict__ Ahi, const ushort* __restrict__ Alo,
    const ushort* __restrict__ Whi, const ushort* __restrict__ Wlo,
    const float* __restrict__ bias,
    ushort* __restrict__ out_hi, ushort* __restrict__ out_lo,
    float* __restrict__ out_f)
{
    __shared__ ushort lds[SPLIT ? 20480 : 10240];
    ushort* Ah = lds;               // 128*40
    ushort* Wh = lds + 5120;
    ushort* Al = lds + (SPLIT ? 10240 : 0);
    ushort* Wl = lds + (SPLIT ? 15360 : 0);

    const int tid = threadIdx.x;
    // bijective XCD swizzle (nwg=4096, %8==0): hw-linear id -> chunked work id
    const int wid = blockIdx.y * 4 + blockIdx.x;
    const int work = (wid & 7) * 512 + (wid >> 3);
    const int m0 = (work >> 2) * 128;
    const int n0 = (work & 3) * 128;
    const int l = tid & 63, w = tid >> 6;
    const int wm = w >> 1, wn = w & 1;
    const int lane16 = l & 15, hi4 = l >> 4;

    f32x4 zz = {0.f, 0.f, 0.f, 0.f};
    f32x4 acc[4][4];
#pragma unroll
    for (int i = 0; i < 4; ++i)
#pragma unroll
        for (int j = 0; j < 4; ++j) acc[i][j] = zz;

    const int row0 = tid >> 2, row1 = row0 + 64;
    const int ck = (tid & 3) * 8;

    for (int k0 = 0; k0 < 512; k0 += 32) {
        short8 ra0 = *(const short8*)&Ahi[(size_t)(m0 + row0) * 512 + k0 + ck];
        short8 ra1 = *(const short8*)&Ahi[(size_t)(m0 + row1) * 512 + k0 + ck];
        short8 rw0 = *(const short8*)&Whi[(size_t)(n0 + row0) * 512 + k0 + ck];
        short8 rw1 = *(const short8*)&Whi[(size_t)(n0 + row1) * 512 + k0 + ck];
        short8 sa0, sa1, sw0, sw1;
        if constexpr (SPLIT) {
            sa0 = *(const short8*)&Alo[(size_t)(m0 + row0) * 512 + k0 + ck];
            sa1 = *(const short8*)&Alo[(size_t)(m0 + row1) * 512 + k0 + ck];
            sw0 = *(const short8*)&Wlo[(size_t)(n0 + row0) * 512 + k0 + ck];
            sw1 = *(const short8*)&Wlo[(size_t)(n0 + row1) * 512 + k0 + ck];
        }
        __syncthreads();
        *(short8*)&Ah[row0 * 40 + ck] = ra0;
        *(short8*)&Ah[row1 * 40 + ck] = ra1;
        *(short8*)&Wh[row0 * 40 + ck] = rw0;
        *(short8*)&Wh[row1 * 40 + ck] = rw1;
        if constexpr (SPLIT) {
            *(short8*)&Al[row0 * 40 + ck] = sa0;
            *(short8*)&Al[row1 * 40 + ck] = sa1;
            *(short8*)&Wl[row0 * 40 + ck] = sw0;
            *(short8*)&Wl[row1 * 40 + ck] = sw1;
        }
        __syncthreads();

        short8 ah[4], bh[4], al_[4], bl_[4];
#pragma unroll
        for (int mi = 0; mi < 4; ++mi)
            ah[mi] = *(const short8*)&Ah[(wm * 64 + mi * 16 + lane16) * 40 + hi4 * 8];
#pragma unroll
        for (int ni = 0; ni < 4; ++ni)
            bh[ni] = *(const short8*)&Wh[(wn * 64 + ni * 16 + lane16) * 40 + hi4 * 8];
        if constexpr (SPLIT) {
#pragma unroll
            for (int mi = 0; mi < 4; ++mi)
                al_[mi] = *(const short8*)&Al[(wm * 64 + mi * 16 + lane16) * 40 + hi4 * 8];
#pragma unroll
            for (int ni = 0; ni < 4; ++ni)
                bl_[ni] = *(const short8*)&Wl[(wn * 64 + ni * 16 + lane16) * 40 + hi4 * 8];
        }
#pragma unroll
        for (int mi = 0; mi < 4; ++mi)
#pragma unroll
            for (int ni = 0; ni < 4; ++ni) {
                acc[mi][ni] = __builtin_amdgcn_mfma_f32_16x16x32_bf16(
                    ah[mi], bh[ni], acc[mi][ni], 0, 0, 0);
                if constexpr (SPLIT) {
                    acc[mi][ni] = __builtin_amdgcn_mfma_f32_16x16x32_bf16(
                        al_[mi], bh[ni], acc[mi][ni], 0, 0, 0);
                    acc[mi][ni] = __builtin_amdgcn_mfma_f32_16x16x32_bf16(
                        ah[mi], bl_[ni], acc[mi][ni], 0, 0, 0);
                }
            }
    }

    // epilogue: C/D frag mapping col=lane&15, row=(lane>>4)*4+reg (m89-verified)
#pragma unroll
    for (int mi = 0; mi < 4; ++mi) {
#pragma unroll
        for (int ni = 0; ni < 4; ++ni) {
            const int col = n0 + wn * 64 + ni * 16 + lane16;
            const float bs = bias[col];
#pragma unroll
            for (int r = 0; r < 4; ++r) {
                const int row = m0 + wm * 64 + mi * 16 + hi4 * 4 + r;
                float v = acc[mi][ni][r] + bs;
                if (MODE == 0) {
                    out_f[(size_t)row * 512 + col] = v;
                } else {
                    const int s = row >> 9, nb = row & 511;
                    const int h = col >> 7, dd = col & 127;
                    const size_t o =
                        (((size_t)nb * H_DIM + h) * S_DIM + s) * HD + dd;
                    if (MODE == 1) {
                        ushort h_, l_;
                        split2(v, h_, l_);
                        out_hi[o] = h_; out_lo[o] = l_;
                    } else {
                        out_hi[o] = f2bf_rne(v);
                    }
                }
            }
        }
    }
}

// ---------------------------------------------------------------------------
// Kernel 4: per-(n,h) transpose vp [s][d] -> vpT [d][s]  (bf16)
// ---------------------------------------------------------------------------
__global__ __launch_bounds__(256) void transpose_v(
    const ushort* __restrict__ vin, ushort* __restrict__ vout)
{
    __shared__ ushort T[128 * 136];
    const int tid = threadIdx.x;
    const int s0 = blockIdx.x * 128;
    const int nh = blockIdx.y;
    const size_t ib = (size_t)nh * S_DIM * HD;

#pragma unroll
    for (int p = 0; p < 8; ++p) {
        int row = (tid >> 4) + p * 16;
        int cc = (tid & 15) * 8;
        *(short8*)&T[row * 136 + cc] =
            *(const short8*)&vin[ib + (size_t)(s0 + row) * HD + cc];
    }
    __syncthreads();
    const int dr = tid >> 1;
    const int sh = (tid & 1) * 64;
#pragma unroll
    for (int j = 0; j < 8; ++j) {
        short8 v;
#pragma unroll
        for (int e = 0; e < 8; ++e)
            ((ushort*)&v)[e] = T[(sh + j * 8 + e) * 136 + dr];
        *(short8*)&vout[ib + (size_t)dr * S_DIM + s0 + sh + j * 8] = v;
    }
}

// ---------------------------------------------------------------------------
// Kernel 5: MFMA flash attention per (s-tile 64, h, n).
// qp/kp: [n][h][s][d] split bf16; vpT: [n][h][d][s] bf16.
// 4 waves; wave w owns 16 s-rows. Q in registers; K hi/lo + V^T in LDS.
// Split QK^T (3 mfma), in-register online softmax (score rows align with
// lane groups for both QK^T-D and PV-D, so m/l/alpha stay in-lane), bf16 PV.
// Output o (S,L,E) as split bf16 hi/lo.
// XCD swizzle: 4 s-blocks sharing a (h,n) head land on one XCD's L2.
// ---------------------------------------------------------------------------
__global__ __launch_bounds__(256) void attn_mfma(
    const ushort* __restrict__ qphi, const ushort* __restrict__ qplo,
    const ushort* __restrict__ kphi, const ushort* __restrict__ kplo,
    const ushort* __restrict__ vpT,
    ushort* __restrict__ ohi, ushort* __restrict__ olo)
{
    __shared__ ushort Kh[64 * 136];
    __shared__ ushort Kl[64 * 136];
    __shared__ ushort VT[128 * 72];
    __shared__ ushort Pl[4 * 16 * 72];

    const int tid = threadIdx.x;
    const int l = tid & 63, w = tid >> 6;
    const int lane16 = l & 15, hi4 = l >> 4;
    // bijective XCD swizzle (nwg=8192, %8==0)
    const int wid = (blockIdx.z * 4 + blockIdx.y) * 4 + blockIdx.x;
    const int work = (wid & 7) * 1024 + (wid >> 3);
    const int s0 = (work & 3) * 64;
    const int h = (work >> 2) & 3;
    const int n = work >> 4;
    const int nh = n * H_DIM + h;
    const size_t qb = (size_t)nh * S_DIM * HD;
    const size_t vb = (size_t)nh * HD * S_DIM;
    const float scale = 0.08838834764831845f;  // 1/sqrt(128)

    // Q fragments in registers (wave's 16 s-rows)
    short8 qh[4], ql[4];
    {
        const size_t rb = qb + (size_t)(s0 + w * 16 + lane16) * HD + hi4 * 8;
#pragma unroll
        for (int ks = 0; ks < 4; ++ks) {
            qh[ks] = *(const short8*)&qphi[rb + ks * 32];
            ql[ks] = *(const short8*)&qplo[rb + ks * 32];
        }
    }

    float mreg[4] = {-1e30f, -1e30f, -1e30f, -1e30f};
    float lreg[4] = {0.f, 0.f, 0.f, 0.f};
    f32x4 zz = {0.f, 0.f, 0.f, 0.f};
    f32x4 Ob[8];
#pragma unroll
    for (int di = 0; di < 8; ++di) Ob[di] = zz;

    ushort* Pw = Pl + w * 1152;  // 16*72

    for (int t0 = 0; t0 < S_DIM; t0 += 64) {
        __syncthreads();
        {   // stage K hi/lo tile [64][136]
            const int row = tid >> 2;
            const int cb = tid & 3;
#pragma unroll
            for (int p = 0; p < 4; ++p) {
                const int chunk = p * 4 + cb;
                const size_t g = qb + (size_t)(t0 + row) * HD + chunk * 8;
                *(short8*)&Kh[row * 136 + chunk * 8] = *(const short8*)&kphi[g];
                *(short8*)&Kl[row * 136 + chunk * 8] = *(const short8*)&kplo[g];
            }
            // stage V^T tile [128][72] (cols t0..t0+63)
            const int dr = tid >> 1;
            const int cb2 = (tid & 1) * 4;
#pragma unroll
            for (int p = 0; p < 4; ++p) {
                const int chunk = cb2 + p;
                const size_t g = vb + (size_t)dr * S_DIM + t0 + chunk * 8;
                *(short8*)&VT[dr * 72 + chunk * 8] = *(const short8*)&vpT[g];
            }
        }
        __syncthreads();

        // QK^T: D[s(16) x t(64)] per wave, split precision
        f32x4 sc[4];
#pragma unroll
        for (int ni = 0; ni < 4; ++ni) sc[ni] = zz;
#pragma unroll
        for (int ks = 0; ks < 4; ++ks) {
#pragma unroll
            for (int ni = 0; ni < 4; ++ni) {
                const int ko = (ni * 16 + lane16) * 136 + ks * 32 + hi4 * 8;
                short8 bh = *(const short8*)&Kh[ko];
                short8 bl = *(const short8*)&Kl[ko];
                sc[ni] = __builtin_amdgcn_mfma_f32_16x16x32_bf16(qh[ks], bh, sc[ni], 0, 0, 0);
                sc[ni] = __builtin_amdgcn_mfma_f32_16x16x32_bf16(ql[ks], bh, sc[ni], 0, 0, 0);
                sc[ni] = __builtin_amdgcn_mfma_f32_16x16x32_bf16(qh[ks], bl, sc[ni], 0, 0, 0);
            }
        }

        // online softmax; lane holds rows hi4*4+r, cols ni*16+lane16
        float pm[4];
#pragma unroll
        for (int r = 0; r < 4; ++r) {
            pm[r] = fmaxf(fmaxf(sc[0][r], sc[1][r]), fmaxf(sc[2][r], sc[3][r])) * scale;
            pm[r] = fmaxf(pm[r], __shfl_xor(pm[r], 1));
            pm[r] = fmaxf(pm[r], __shfl_xor(pm[r], 2));
            pm[r] = fmaxf(pm[r], __shfl_xor(pm[r], 4));
            pm[r] = fmaxf(pm[r], __shfl_xor(pm[r], 8));
        }
#pragma unroll
        for (int r = 0; r < 4; ++r) {
            const float mn = fmaxf(mreg[r], pm[r]);
            const float alpha = __expf(mreg[r] - mn);
            mreg[r] = mn;
            float ps = 0.f;
#pragma unroll
            for (int ni = 0; ni < 4; ++ni) {
                float p = __expf(sc[ni][r] * scale - mn);
                ps += p;
                Pw[(hi4 * 4 + r) * 72 + ni * 16 + lane16] = f2bf_rne(p);
            }
            ps += __shfl_xor(ps, 1);
            ps += __shfl_xor(ps, 2);
            ps += __shfl_xor(ps, 4);
            ps += __shfl_xor(ps, 8);
            lreg[r] = lreg[r] * alpha + ps;
#pragma unroll
            for (int di = 0; di < 8; ++di) Ob[di][r] *= alpha;
        }

        // PV: O[s(16) x d(128)] += P[s x 64] * V[64 x d]
#pragma unroll
        for (int ks = 0; ks < 2; ++ks) {
            short8 pa = *(const short8*)&Pw[lane16 * 72 + ks * 32 + hi4 * 8];
#pragma unroll
            for (int di = 0; di < 8; ++di) {
                short8 bv = *(const short8*)&VT[(di * 16 + lane16) * 72 + ks * 32 + hi4 * 8];
                Ob[di] = __builtin_amdgcn_mfma_f32_16x16x32_bf16(pa, bv, Ob[di], 0, 0, 0);
            }
        }
    }

    // epilogue: o (S,L,E) split bf16
#pragma unroll
    for (int r = 0; r < 4; ++r) {
        const float inv = 1.0f / lreg[r];
        const int so = s0 + w * 16 + hi4 * 4 + r;
#pragma unroll
        for (int di = 0; di < 8; ++di) {
            float v = Ob[di][r] * inv;
            ushort h_, l_;
            split2(v, h_, l_);
            const size_t o = ((size_t)so * L_DIM + n) * E_DIM + h * HD + di * 16 + lane16;
            ohi[o] = h_; olo[o] = l_;
        }
    }
}

// ---------------------------------------------------------------------------
// Buffer lifetime plan (7 x 128MiB bf16 buffers + 4MiB weights = 900MiB):
//   B0 xhi      -> (after vp GEMM consumes it) ohi
//   B1 Qhi      -> (after qp GEMM)             kphi
//   B2 Qlo      -> (after qp GEMM)             kplo
//   B3 Khi      -> (after kp GEMM)             vpn  -> (after transpose) olo
//   B4 Klo      -> (after kp GEMM)             vpT
//   B5 chunk-sum scratch (33.5MB, consumed by banded_out) -> qphi
//   B6 qplo
// ---------------------------------------------------------------------------
extern "C" void kernel_launch(void* const* d_in, const int* in_sizes, int n_in,
                              void* d_out, int out_size, void* d_ws, size_t ws_size,
                              hipStream_t stream) {
    (void)in_sizes; (void)n_in; (void)out_size; (void)ws_size;
    const float* x   = (const float*)d_in[0];
    const float* a   = (const float*)d_in[1];
    const float* b   = (const float*)d_in[2];
    const float* c   = (const float*)d_in[3];
    const float* d   = (const float*)d_in[4];
    const float* ipw = (const float*)d_in[5];
    const float* ipb = (const float*)d_in[6];
    const float* ow  = (const float*)d_in[7];
    const float* ob  = (const float*)d_in[8];
    const int* n1    = (const int*)d_in[9];
    const int* n2    = (const int*)d_in[10];

    ushort* W0 = (ushort*)d_ws;
    const size_t BUF = (size_t)M_DIM * E_DIM;  // 67108864 elems (128MiB bf16)
    ushort* B0 = W0;
    ushort* B1 = W0 + 1 * BUF;
    ushort* B2 = W0 + 2 * BUF;
    ushort* B3 = W0 + 3 * BUF;
    ushort* B4 = W0 + 4 * BUF;
    ushort* B5 = W0 + 5 * BUF;
    ushort* B6 = W0 + 6 * BUF;
    ushort* WH = W0 + 7 * BUF;          // 1048576 elems
    ushort* WL = WH + 1048576;

    ushort *xhi = B0, *Qhi = B1, *Qlo = B2, *Khi = B3, *Klo = B4;
    ushort *qphi = B5, *qplo = B6;
    ushort *kphi = B1, *kplo = B2;      // reuse Q after qp GEMM
    ushort *vpn = B3, *vpT = B4;        // reuse K after kp GEMM
    ushort *ohi = B0, *olo = B3;        // reuse xhi/vpn after attention inputs done
    float* CS = (float*)B5;             // 8.4M floats, consumed before qp GEMM

    // 1a) chunk partial sums + x -> bf16
    banded_chunksums<<<dim3(2, 256, NCH), 256, 0, stream>>>(
        x, a, b, c, d, CS, xhi);
    // 1b) banded Q/K outputs (split bf16)
    banded_out<<<dim3(2, 256, NCH), 256, 0, stream>>>(
        x, a, b, c, d, n1, n2, CS, Qhi, Qlo, Khi, Klo);

    // 2) weight splits
    split_weights<<<dim3(4096), 256, 0, stream>>>(ipw, ow, WH, WL);

    // 3) projections into per-head layout [L][H][S][HD]
    gemm_mfma<1, 1><<<dim3(4, 1024), 256, 0, stream>>>(
        Qhi, Qlo, WH, WL, ipb, qphi, qplo, nullptr);
    gemm_mfma<1, 1><<<dim3(4, 1024), 256, 0, stream>>>(
        Khi, Klo, WH + 262144, WL + 262144, ipb + 512, kphi, kplo, nullptr);
    gemm_mfma<2, 0><<<dim3(4, 1024), 256, 0, stream>>>(
        xhi, nullptr, WH + 524288, nullptr, ipb + 1024, vpn, nullptr, nullptr);

    // 4) V transpose per head: [n][h][s][d] -> [n][h][d][s]
    transpose_v<<<dim3(2, 2048), 256, 0, stream>>>(vpn, vpT);

    // 5) attention -> o (S,L,E) split bf16
    attn_mfma<<<dim3(4, 4, 512), 256, 0, stream>>>(
        qphi, qplo, kphi, kplo, vpT, ohi, olo);

    // 6) out projection -> fp32 d_out
    gemm_mfma<0, 1><<<dim3(4, 1024), 256, 0, stream>>>(
        ohi, olo, WH + 786432, WL + 786432, ob, nullptr, nullptr, (float*)d_out);
}